// Round 9
// baseline (130.686 us; speedup 1.0000x reference)
//
#include <hip/hip_runtime.h>
#include <hip/hip_bf16.h>

// BottleneckAdapter: out = residual + Wup·( swish(Wl1·n+bl1) * (Wl2·n+bl2) ),
// n = LN( (Wdown·Wproj)·x ).  W_comb = Wdown@Wproj precomputed per-launch.
// Dims: B=16 S=2048 C=768 Q=1024 D=64 -> ROWS=32768.
//
// R9: defeat load-sinking with global_load_lds everywhere it matters.
//  k_act: phase A = pure 48KB DMA (x kept f32 in LDS, XOR-swizzled source,
//         bf16 convert during MFMA fragment reads). 12 DMAs/wave in flight.
//  k_up : MFMA -> bf16 bounce(32KB); res via 4-slot LDS ring of row-DMAs with
//         counted vmcnt {3,4,5,6..6,5,4,3} (never 0 mid-loop); raw s_barrier +
//         lgkmcnt(0) so barriers never drain the vm queue; contiguous 4KB/row
//         res reads + out writes.

#define CDIM 768
#define QDIM 1024

typedef __attribute__((ext_vector_type(8))) short bf16x8;
typedef __attribute__((ext_vector_type(4))) float f32x4;

#define WAITV(n) asm volatile("s_waitcnt vmcnt(" #n ")" ::: "memory")
#define SCHED0() __builtin_amdgcn_sched_barrier(0)

__device__ __forceinline__ ushort f2bf(float f) {
  union { float f; unsigned u; } v; v.f = f;
  unsigned r = v.u + 0x7fffu + ((v.u >> 16) & 1u);   // RNE
  return (ushort)(r >> 16);
}

__device__ __forceinline__ void gload16(const float* g, float* lds) {
  __builtin_amdgcn_global_load_lds(
      (const __attribute__((address_space(1))) void*)g,
      (__attribute__((address_space(3))) void*)lds, 16, 0, 0);
}

// ---- K1: partial W_comb, 8 q-chunks. part[qc][c][d] (8 x 768 x 64 f32)
__global__ void k_wcomb(const float* __restrict__ Wproj, const float* __restrict__ Wdown,
                        float* __restrict__ part) {
  int bid = blockIdx.x;                 // 768 = 12 cb * 8 db * 8 qc
  int cb = bid % 12, db = (bid / 12) % 8, qc = bid / 96;
  int l = threadIdx.x;                  // 64
  int c = cb * 64 + l;
  float acc[8];
  #pragma unroll
  for (int i = 0; i < 8; ++i) acc[i] = 0.f;
  int q0 = qc * 128;
  for (int q = q0; q < q0 + 128; ++q) {
    float xp = Wproj[q * CDIM + c];
    #pragma unroll
    for (int i = 0; i < 8; ++i)
      acc[i] = fmaf(Wdown[(db * 8 + i) * QDIM + q], xp, acc[i]);
  }
  #pragma unroll
  for (int i = 0; i < 8; ++i)
    part[((size_t)qc * CDIM + c) * 64 + db * 8 + i] = acc[i];
}

// ---- K2: sum partials + arrange weights into MFMA fragment order (bf16).
// element (lane l, j) of tile (ks,nf) = M[16*nf+(l&15)][32*ks + 8*(l>>4)+j]
__global__ void k_arrange(const float* __restrict__ part, const float* __restrict__ Wup,
                          const float* __restrict__ Wl1, const float* __restrict__ Wl2,
                          ushort* __restrict__ wcf, ushort* __restrict__ wupf,
                          ushort* __restrict__ wl1f, ushort* __restrict__ wl2f) {
  int idx = blockIdx.x * 256 + threadIdx.x;      // 480*256 = 122880
  if (idx < 49152) {                             // wcf
    int i0 = idx;
    int j = i0 & 7, l = (i0 >> 3) & 63, t = i0 >> 9;
    int g = l >> 4, r16 = l & 15;
    int nf = t & 3, ks = t >> 2;
    int k = 32 * ks + 8 * g + j, n = 16 * nf + r16;
    float s = 0.f;
    #pragma unroll
    for (int qc = 0; qc < 8; ++qc) s += part[((size_t)qc * CDIM + k) * 64 + n];
    wcf[i0] = f2bf(s);
  } else if (idx < 49152 + 65536) {              // wupf
    int i2 = idx - 49152;
    int j = i2 & 7, l = (i2 >> 3) & 63, t = i2 >> 9;
    int g = l >> 4, r16 = l & 15;
    int ks = t & 1, nf = t >> 1;
    int k = 32 * ks + 8 * g + j, n = 16 * nf + r16;
    wupf[i2] = f2bf(Wup[n * 64 + k]);
  } else if (idx < 49152 + 65536 + 4096) {       // wl1f
    int i3 = idx - (49152 + 65536);
    int j = i3 & 7, l = (i3 >> 3) & 63, t = i3 >> 9;
    int g = l >> 4, r16 = l & 15;
    int nf = t & 3, ks = t >> 2;
    int k = 32 * ks + 8 * g + j, e = 16 * nf + r16;
    wl1f[i3] = f2bf(Wl1[e * 64 + k]);
  } else {                                       // wl2f
    int i4 = idx - (49152 + 65536 + 4096);
    int j = i4 & 7, l = (i4 >> 3) & 63, t = i4 >> 9;
    int g = l >> 4, r16 = l & 15;
    int nf = t & 3, ks = t >> 2;
    int k = 32 * ks + 8 * g + j, e = 16 * nf + r16;
    wl2f[i4] = f2bf(Wl2[e * 64 + k]);
  }
}

// ---- K_A: x -> down-proj -> LN -> SwiGLU -> a[] (bf16). 16 rows/WG, 4 waves.
// Phase A is a pure 48KB DMA; x stays f32 in LDS (converted in phase B).
// LDS layout (union, 49152B): x_f32 [16][768] | d@0 | n@4608 | a@8192.
// x stored with 16B-unit swizzle: phys unit u holds logical u^(row&7)
// (pre-swizzled on the GLOBAL source; dest linear per gload_lds rules).
__global__ __launch_bounds__(256, 3)
void k_act(const float* __restrict__ xg,
           const float* __restrict__ gamma, const float* __restrict__ beta,
           const float* __restrict__ bl1, const float* __restrict__ bl2,
           const ushort* __restrict__ wcf,
           const ushort* __restrict__ wl1f, const ushort* __restrict__ wl2f,
           ushort* __restrict__ ag) {
  __shared__ alignas(16) ushort smem[24576];    // 49152 B
  float  (*d_lds)[68]  = reinterpret_cast<float (*)[68]>(smem);
  ushort (*n_lds)[72]  = reinterpret_cast<ushort(*)[72]>(reinterpret_cast<char*>(smem) + 4608);
  ushort (*a_lds)[72]  = reinterpret_cast<ushort(*)[72]>(reinterpret_cast<char*>(smem) + 8192);
  float* xf = reinterpret_cast<float*>(smem);   // [16][768]

  const int tid = threadIdx.x;
  const int w = tid >> 6, l = tid & 63, g = l >> 4, r16 = l & 15;
  const int row0 = blockIdx.x * 16;

  // Phase A: 12 x 4KB DMA sweeps; all 12 in flight per wave.
  #pragma unroll
  for (int i = 0; i < 12; ++i) {
    int f4 = i * 256 + tid;                    // 16B unit index in tile
    int r  = f4 / 192;
    int u  = f4 - r * 192;
    const float* src = xg + (size_t)(row0 + r) * CDIM + ((u ^ (r & 7)) << 2);
    gload16(src, xf + (size_t)(i * 256 + (w << 6)) * 4);  // wave-linear dest
  }
  __syncthreads();   // vmcnt(0)+lgkm+barrier: x ready for all waves

  // Phase B: d = x * Wcomb^T; convert f32->bf16 while building fragments.
  f32x4 dacc = {0.f, 0.f, 0.f, 0.f};
  const int rx = r16 & 7;
  const float* rowp = xf + r16 * 768;
  #pragma unroll 8
  for (int ks = 0; ks < 24; ++ks) {
    int u0 = ks * 8 + 2 * g;
    f32x4 xa = *reinterpret_cast<const f32x4*>(rowp + ((u0 ^ rx) << 2));
    f32x4 xb = *reinterpret_cast<const f32x4*>(rowp + (((u0 + 1) ^ rx) << 2));
    union { bf16x8 v; __hip_bfloat16 h[8]; } fa;
    fa.h[0] = __float2bfloat16(xa[0]); fa.h[1] = __float2bfloat16(xa[1]);
    fa.h[2] = __float2bfloat16(xa[2]); fa.h[3] = __float2bfloat16(xa[3]);
    fa.h[4] = __float2bfloat16(xb[0]); fa.h[5] = __float2bfloat16(xb[1]);
    fa.h[6] = __float2bfloat16(xb[2]); fa.h[7] = __float2bfloat16(xb[3]);
    bf16x8 b = *reinterpret_cast<const bf16x8*>(wcf + ((size_t)(ks * 4 + w) * 64 + l) * 8);
    dacc = __builtin_amdgcn_mfma_f32_16x16x32_bf16(fa.v, b, dacc, 0, 0, 0);
  }
  __syncthreads();                             // x reads done before d overwrite
  #pragma unroll
  for (int rg = 0; rg < 4; ++rg) d_lds[4 * g + rg][16 * w + r16] = dacc[rg];
  __syncthreads();

  // Phase C: LayerNorm over D=64.
  {
    int row = 4 * w + g;
    f32x4 v = *reinterpret_cast<const f32x4*>(&d_lds[row][4 * r16]);
    float s  = v[0] + v[1] + v[2] + v[3];
    float sq = v[0]*v[0] + v[1]*v[1] + v[2]*v[2] + v[3]*v[3];
    #pragma unroll
    for (int m = 1; m < 16; m <<= 1) {
      s  += __shfl_xor(s, m, 64);
      sq += __shfl_xor(sq, m, 64);
    }
    float mu  = s * (1.f / 64.f);
    float var = sq * (1.f / 64.f) - mu * mu;
    float rs  = rsqrtf(var + 1e-5f);
    const float4 gm = *reinterpret_cast<const float4*>(gamma + 4 * r16);
    const float4 bt = *reinterpret_cast<const float4*>(beta  + 4 * r16);
    ushort4 nb;
    nb.x = f2bf((v[0] - mu) * rs * gm.x + bt.x);
    nb.y = f2bf((v[1] - mu) * rs * gm.y + bt.y);
    nb.z = f2bf((v[2] - mu) * rs * gm.z + bt.z);
    nb.w = f2bf((v[3] - mu) * rs * gm.w + bt.w);
    *reinterpret_cast<ushort4*>(&n_lds[row][4 * r16]) = nb;
  }
  __syncthreads();

  // Phase D: SwiGLU -> a_lds.
  {
    bf16x8 a0 = *reinterpret_cast<const bf16x8*>(&n_lds[r16][8 * g]);
    bf16x8 a1 = *reinterpret_cast<const bf16x8*>(&n_lds[r16][32 + 8 * g]);
    bf16x8 b10 = *reinterpret_cast<const bf16x8*>(wl1f + ((size_t)(0 * 4 + w) * 64 + l) * 8);
    bf16x8 b11 = *reinterpret_cast<const bf16x8*>(wl1f + ((size_t)(1 * 4 + w) * 64 + l) * 8);
    bf16x8 b20 = *reinterpret_cast<const bf16x8*>(wl2f + ((size_t)(0 * 4 + w) * 64 + l) * 8);
    bf16x8 b21 = *reinterpret_cast<const bf16x8*>(wl2f + ((size_t)(1 * 4 + w) * 64 + l) * 8);
    f32x4 z = {0.f, 0.f, 0.f, 0.f};
    f32x4 acc1 = __builtin_amdgcn_mfma_f32_16x16x32_bf16(a0, b10, z, 0, 0, 0);
    acc1 = __builtin_amdgcn_mfma_f32_16x16x32_bf16(a1, b11, acc1, 0, 0, 0);
    f32x4 acc2 = __builtin_amdgcn_mfma_f32_16x16x32_bf16(a0, b20, z, 0, 0, 0);
    acc2 = __builtin_amdgcn_mfma_f32_16x16x32_bf16(a1, b21, acc2, 0, 0, 0);
    float bv1 = bl1[16 * w + r16];
    float bv2 = bl2[16 * w + r16];
    #pragma unroll
    for (int rg = 0; rg < 4; ++rg) {
      float o1 = acc1[rg] + bv1;
      float o2 = acc2[rg] + bv2;
      float sw = o1 / (1.f + __expf(-o1));       // swish
      a_lds[4 * g + rg][16 * w + r16] = f2bf(sw * o2);
    }
  }
  __syncthreads();

  // Contiguous ag dump: 128 threads x 16B = 2KB.
  if (tid < 128) {
    int r = tid >> 3, c = 8 * (tid & 7);
    bf16x8 v = *reinterpret_cast<const bf16x8*>(&a_lds[r][c]);
    *reinterpret_cast<bf16x8*>(ag + (size_t)(row0 + r) * 64 + c) = v;
  }
}

// ---- K_B: out = res + a * Wup^T.  bf16 bounce + DMA res ring, counted vmcnt.
// 2048 blocks x 256 thr, 3 blocks/CU. Per block: 16 rows x 1024 cols.
// Stream: 16 sweeps (1 row = 4KB each); res DMA'd 3 sweeps ahead into a
// 4-slot LDS ring; per-sweep counted vmcnt (never 0 mid-loop).
__global__ __launch_bounds__(256, 3)
void k_up(const ushort* __restrict__ ag, const float* __restrict__ resg,
          const ushort* __restrict__ wupf, float* __restrict__ outg) {
  __shared__ alignas(16) ushort a_lds[16][68];     // 2176 B
  __shared__ alignas(16) ushort bounce[16][1024];  // 32 KB (bf16 up-values)
  __shared__ alignas(16) float  ring[4][1024];     // 16 KB res ring
  const int tid = threadIdx.x;
  const int w = tid >> 6, l = tid & 63, g = l >> 4, r16 = l & 15;
  const int row0 = blockIdx.x * 16;

  // stage a-tile (16x64 bf16 = 2KB)
  {
    int e = tid * 4;
    int r = e >> 6, c = e & 63;
    ushort4 v = *reinterpret_cast<const ushort4*>(ag + (size_t)(row0 + r) * 64 + c);
    *reinterpret_cast<ushort4*>(&a_lds[r][c]) = v;
  }
  asm volatile("s_waitcnt lgkmcnt(0)" ::: "memory");
  __builtin_amdgcn_s_barrier();                    // no vmcnt drain
  SCHED0();

  // Prologue: res DMAs for sweeps 0..2 (stay in flight under MFMA phase).
  #pragma unroll
  for (int s = 0; s < 3; ++s)
    gload16(resg + (size_t)(row0 + s) * QDIM + 4 * tid, &ring[s][w << 8]);
  SCHED0();

  // MFMA phase: wave w -> cols 256w..256w+255 (nf = 16w+i), acc -> bf16 bounce.
  {
    const bf16x8 af0 = *reinterpret_cast<const bf16x8*>(&a_lds[r16][8 * g]);
    const bf16x8 af1 = *reinterpret_cast<const bf16x8*>(&a_lds[r16][32 + 8 * g]);
    #pragma unroll
    for (int i = 0; i < 16; ++i) {
      size_t nf = 16 * w + i;
      bf16x8 b0 = *reinterpret_cast<const bf16x8*>(wupf + ((nf * 2 + 0) * 64 + l) * 8);
      bf16x8 b1 = *reinterpret_cast<const bf16x8*>(wupf + ((nf * 2 + 1) * 64 + l) * 8);
      f32x4 t = {0.f, 0.f, 0.f, 0.f};
      t = __builtin_amdgcn_mfma_f32_16x16x32_bf16(b0, af0, t, 0, 0, 0);
      t = __builtin_amdgcn_mfma_f32_16x16x32_bf16(b1, af1, t, 0, 0, 0);
      ushort4 ub;
      ub.x = f2bf(t[0]); ub.y = f2bf(t[1]); ub.z = f2bf(t[2]); ub.w = f2bf(t[3]);
      int q = 64 * w + 4 * i + g;                  // logical quad (4 cols)
      int p = q ^ ((r16 & 7) << 2);                // bank swizzle
      *reinterpret_cast<ushort4*>(&bounce[r16][p << 2]) = ub;
    }
  }
  asm volatile("s_waitcnt lgkmcnt(0)" ::: "memory");
  __builtin_amdgcn_s_barrier();                    // bounce visible; vm queue intact
  SCHED0();

  // Stream: sweep s = row row0+s. Counted vmcnt so DMAs issued 3 ahead.
  #pragma unroll
  for (int s = 0; s < 16; ++s) {
    SCHED0();
    if (s < 13)
      gload16(resg + (size_t)(row0 + s + 3) * QDIM + 4 * tid, &ring[(s + 3) & 3][w << 8]);
    SCHED0();
    // newer-than-g_s ops at this point: see derivation (stores + gloads).
    if      (s == 0)  WAITV(3);
    else if (s == 1)  WAITV(4);
    else if (s == 2)  WAITV(5);
    else if (s <= 12) WAITV(6);
    else if (s == 13) WAITV(5);
    else if (s == 14) WAITV(4);
    else              WAITV(3);
    SCHED0();
    f32x4 rv = *reinterpret_cast<const f32x4*>(&ring[s & 3][tid << 2]);
    int p = tid ^ ((s & 7) << 2);
    ushort4 ub = *reinterpret_cast<const ushort4*>(&bounce[s][p << 2]);
    union { float f; unsigned u; } c0, c1, c2, c3;
    c0.u = (unsigned)ub.x << 16; c1.u = (unsigned)ub.y << 16;
    c2.u = (unsigned)ub.z << 16; c3.u = (unsigned)ub.w << 16;
    f32x4 o;
    o[0] = rv[0] + c0.f; o[1] = rv[1] + c1.f;
    o[2] = rv[2] + c2.f; o[3] = rv[3] + c3.f;
    *reinterpret_cast<f32x4*>(outg + (size_t)(row0 + s) * QDIM + 4 * tid) = o;
  }
}

extern "C" void kernel_launch(void* const* d_in, const int* in_sizes, int n_in,
                              void* d_out, int out_size, void* d_ws, size_t ws_size,
                              hipStream_t stream) {
  (void)in_sizes; (void)n_in; (void)out_size; (void)ws_size;
  const float* x     = (const float*)d_in[0];
  const float* resid = (const float*)d_in[1];
  const float* Wproj = (const float*)d_in[2];
  const float* Wdown = (const float*)d_in[3];
  const float* gamma = (const float*)d_in[4];
  const float* beta  = (const float*)d_in[5];
  const float* Wl1   = (const float*)d_in[6];
  const float* bl1   = (const float*)d_in[7];
  const float* Wl2   = (const float*)d_in[8];
  const float* bl2   = (const float*)d_in[9];
  const float* Wup   = (const float*)d_in[10];
  float* out = (float*)d_out;

  char* ws = (char*)d_ws;
  float*  part = (float*)(ws);                   // 1,572,864 B
  ushort* wcf  = (ushort*)(ws + 1572864);        //    98,304 B
  ushort* wupf = (ushort*)(ws + 1671168);        //   131,072 B
  ushort* wl1f = (ushort*)(ws + 1802240);        //     8,192 B
  ushort* wl2f = (ushort*)(ws + 1810432);        //     8,192 B
  ushort* ag   = (ushort*)(ws + 1818624);        // 4,194,304 B

  k_wcomb  <<<768, 64, 0, stream>>>(Wproj, Wdown, part);
  k_arrange<<<480, 256, 0, stream>>>(part, Wup, Wl1, Wl2, wcf, wupf, wl1f, wl2f);
  k_act    <<<2048, 256, 0, stream>>>(x, gamma, beta, bl1, bl2, wcf, wl1f, wl2f, ag);
  k_up     <<<2048, 256, 0, stream>>>(ag, resid, wupf, out);
}